// Round 16
// baseline (5638.396 us; speedup 1.0000x reference)
//
#include <hip/hip_runtime.h>
#include <cstdint>
#include <cstddef>

typedef __bf16 bf16;
typedef __bf16 bf16x8 __attribute__((ext_vector_type(8)));
typedef float f32x4 __attribute__((ext_vector_type(4)));

#define DEVINL __device__ __forceinline__

typedef const __attribute__((address_space(1))) void* as1cv;
typedef __attribute__((address_space(3))) void* as3v;

DEVINL void gload16(const bf16* g, bf16* l) {
    __builtin_amdgcn_global_load_lds((as1cv)g, (as3v)l, 16, 0, 0);
}

// ---------------- dims ----------------
static constexpr int Lh = 12, Hh = 12, Dh = 768, Nh = 197, Mh = 3072, Bh = 16;
static constexpr int BN   = Bh * Nh;     // 3152 token rows
static constexpr int NPAT = Bh * 196;    // 3136 patch rows
static constexpr int HD   = Hh * Dh;     // 9216
static constexpr int QKN  = 2 * HD;      // 18432 (fallback fused Q|K layout)
static constexpr int QKV3 = 3 * HD;      // 27648 fused Q|K|V cols
static constexpr int NP   = 256;         // padded token dim (attention)
static constexpr int FHN  = Hh * Nh;     // 2364
static constexpr int FP   = 2368;        // padded H*N (mult of 64)
static constexpr size_t SEC = (size_t)Bh * 196 * Dh;  // one output section (f32)
static constexpr long LS3 = (long)QKV3 * Dh;          // fused weight layer stride
static constexpr long PART = (long)BN * Dh;           // split-K partial stride (f32 elems)

// ============================================================
// 128x128-tile GEMM, BK=64, XOR-swizzled LDS (T2, rule #21 both-sides).
// ============================================================
template<int AF32, int BF32, int OUTBF, int BIAS, int ACT, int ZFILL>
__global__ __launch_bounds__(256, 4) void gemm_bt(
    const void* __restrict__ Av, long sAy, long sAz, int lda,
    const void* __restrict__ Bv, long sBy, long sBz, int ldb,
    void* __restrict__ Cv, long sCy, long sCz, int ldc,
    const float* __restrict__ bias, long sBiasY,
    int Mv, int Nv, int K, int tilesN, int kChunk)
{
    __shared__ __align__(16) bf16 Asm[128 * 64];
    __shared__ __align__(16) bf16 Bsm[128 * 64];
    const int tm = blockIdx.x / tilesN, tn = blockIdx.x % tilesN;
    const long aoff = (long)blockIdx.y * sAy + (long)blockIdx.z * sAz + (long)tm * 128 * lda;
    const long boff = (long)blockIdx.y * sBy + (long)blockIdx.z * sBz + (long)tn * 128 * ldb;
    const int tid = threadIdx.x;
    const int lane = tid & 63, wid = tid >> 6;
    const int ar = tid >> 3;                         // 32 rows per staging pass
    const int ac = (tid & 7) << 3;                   // linear chunk (f32 path src)
    const int acs = (((tid & 7) ^ ((tid >> 3) & 7)) << 3); // swizzled src chunk (bf16 path)
    const bf16* Ag = (const bf16*)Av + aoff + (long)ar * lda + acs;
    const bf16* Bg = (const bf16*)Bv + boff + (long)ar * ldb + acs;
    const float* Af = (const float*)Av + aoff + (long)ar * lda + ac;
    const float* Bf = (const float*)Bv + boff + (long)ar * ldb + ac;
    bf16* lA = Asm + wid * 512;
    bf16* lB = Bsm + wid * 512;
    const int mw = (wid >> 1) * 64, nw = (wid & 1) * 64;
    const int fr = lane & 15, fq = lane >> 4;
    const int kBeg = kChunk ? blockIdx.y * kChunk : 0;
    const int kEnd = kChunk ? min(K, kBeg + kChunk) : K;
    f32x4 acc[4][4] = {};
    for (int k0 = kBeg; k0 < kEnd; k0 += 64) {
        if (AF32) {
#pragma unroll
            for (int jp = 0; jp < 4; jp++) {
                const float* p0 = Af + (long)jp * 32 * lda + k0;
                f32x4 a0 = *(const f32x4*)p0, a1 = *(const f32x4*)(p0 + 4);
                bf16x8 r0;
#pragma unroll
                for (int i = 0; i < 4; i++) { r0[i] = (bf16)a0[i]; r0[i + 4] = (bf16)a1[i]; }
                *(bf16x8*)&Asm[(jp * 32 + ar) * 64 + (ac ^ ((ar & 7) << 3))] = r0;
            }
        } else {
#pragma unroll
            for (int jp = 0; jp < 4; jp++)
                gload16(Ag + (long)jp * 32 * lda + k0, lA + jp * 2048);
        }
        if (BF32) {
#pragma unroll
            for (int jp = 0; jp < 4; jp++) {
                const float* p0 = Bf + (long)jp * 32 * ldb + k0;
                f32x4 a0 = *(const f32x4*)p0, a1 = *(const f32x4*)(p0 + 4);
                bf16x8 r0;
#pragma unroll
                for (int i = 0; i < 4; i++) { r0[i] = (bf16)a0[i]; r0[i + 4] = (bf16)a1[i]; }
                *(bf16x8*)&Bsm[(jp * 32 + ar) * 64 + (ac ^ ((ar & 7) << 3))] = r0;
            }
        } else {
#pragma unroll
            for (int jp = 0; jp < 4; jp++)
                gload16(Bg + (long)jp * 32 * ldb + k0, lB + jp * 2048);
        }
        __syncthreads();
#pragma unroll
        for (int ks = 0; ks < 2; ks++) {
            bf16x8 af[4], bv[4];
#pragma unroll
            for (int i = 0; i < 4; i++) {
                const int rl = mw + i * 16 + fr;
                af[i] = *(const bf16x8*)&Asm[rl * 64 + ((((ks << 2) | fq) ^ (rl & 7)) << 3)];
            }
#pragma unroll
            for (int j = 0; j < 4; j++) {
                const int rl = nw + j * 16 + fr;
                bv[j] = *(const bf16x8*)&Bsm[rl * 64 + ((((ks << 2) | fq) ^ (rl & 7)) << 3)];
            }
#pragma unroll
            for (int i = 0; i < 4; i++)
#pragma unroll
                for (int j = 0; j < 4; j++)
                    acc[i][j] = __builtin_amdgcn_mfma_f32_16x16x32_bf16(af[i], bv[j], acc[i][j], 0, 0, 0);
        }
        __syncthreads();
    }
    const long cb = (long)blockIdx.y * sCy + (long)blockIdx.z * sCz;
    const float* biasp = bias ? bias + (long)blockIdx.y * sBiasY : nullptr;
#pragma unroll
    for (int i = 0; i < 4; i++) {
        const int row0 = tm * 128 + mw + i * 16 + fq * 4;
#pragma unroll
        for (int j = 0; j < 4; j++) {
            const int col = tn * 128 + nw + j * 16 + fr;
            const bool cok = (col < Nv);
            if (!cok && !ZFILL) continue;
            float bc = (BIAS == 1 && cok) ? biasp[col] : 0.f;
#pragma unroll
            for (int r = 0; r < 4; r++) {
                const int rr = row0 + r;
                if (rr >= Mv) continue;
                float v;
                if (cok) {
                    v = acc[i][j][r];
                    if (BIAS == 1) v += bc;
                    if (BIAS == 2) v += biasp[rr];
                    if (ACT) v = 0.5f * v * (1.f + erff(v * 0.70710678118654752f));
                } else v = 0.f;
                const long ci = cb + (long)rr * ldc + col;
                if (OUTBF) ((bf16*)Cv)[ci] = (bf16)v;
                else       ((float*)Cv)[ci] = v;
            }
        }
    }
}

// ============================================================
// Merged: fused scores+softmax (rt<2) AND V-transpose (rt>=2).
// rt<2: P[bh][n][m] = softmax_m(Q_bh[n]·K_bh[m]/14)  (BK=64, swizzled LDS)
// rt>=2: two 64x64 V-transpose tiles (one per 256-thr half) ->
//        vT[b,h,e,n] = qkvb[b*197+n][2HD+h*768+e], n>=197 -> 0.
// Same work items as the former separate kernels -> identical output.
// ============================================================
__global__ __launch_bounds__(512, 2) void qksoftv_k(
    const bf16* __restrict__ qkb, bf16* __restrict__ P, bf16* __restrict__ vT)
{
    __shared__ __align__(16) bf16 Qs[128 * 64];
    __shared__ __align__(16) bf16 Ks[256 * 64];
    __shared__ float redM[2][64][4];
    __shared__ float redS[2][64][4];
    const int rt = blockIdx.x, h = blockIdx.y, b = blockIdx.z;
    const int tid = threadIdx.x;

    if (rt >= 2) {
        // ---- V-transpose: tile tl = (rt-2)*2 + half ----
        const int half = tid >> 8;
        const int tid2 = tid & 255;
        const int tl = ((rt - 2) << 1) | half;
        const int eb = (tl >> 2) << 6;
        const int nb = (tl & 3) << 6;
        bf16* t = half ? Ks : Qs;                  // each half: 64*72 bf16 region
        const int lr = tid2 >> 2;
        const int lc = (tid2 & 3) << 4;
        const int n = nb + lr;
        if (n < Nh) {
            const bf16* src = qkb + (size_t)(b * Nh + n) * QKV3 + 2 * HD + h * Dh + eb + lc;
            *(bf16x8*)&t[lr * 72 + lc] = *(const bf16x8*)src;
            *(bf16x8*)&t[lr * 72 + lc + 8] = *(const bf16x8*)(src + 8);
        } else {
            bf16x8 z = {};
            *(bf16x8*)&t[lr * 72 + lc] = z; *(bf16x8*)&t[lr * 72 + lc + 8] = z;
        }
        __syncthreads();
        bf16* dst = vT + ((size_t)(b * Hh + h) * Dh + eb + lr) * NP + nb + lc;
        bf16x8 o0, o1;
#pragma unroll
        for (int j = 0; j < 8; j++) { o0[j] = t[(lc + j) * 72 + lr]; o1[j] = t[(lc + 8 + j) * 72 + lr]; }
        *(bf16x8*)dst = o0; *(bf16x8*)(dst + 8) = o1;
        return;
    }

    // ---- qksoft body (unchanged) ----
    const int lane = tid & 63, wid = tid >> 6;
    const int wr = wid >> 2, wc = wid & 3;
    const int fr = lane & 15, fq = lane >> 4;
    const int ar = tid >> 3;
    const int acs = (((tid & 7) ^ ((tid >> 3) & 7)) << 3);
    const bf16* Qg = qkb + ((size_t)b * Nh + rt * 128 + ar) * QKV3 + h * Dh + acs;
    const bf16* Kg = qkb + ((size_t)b * Nh + ar) * QKV3 + HD + h * Dh + acs;
    bf16* lQ = Qs + wid * 512;
    bf16* lK = Ks + wid * 512;
    f32x4 acc[4][4] = {};
    for (int k0 = 0; k0 < 768; k0 += 64) {
#pragma unroll
        for (int jp = 0; jp < 2; jp++)
            gload16(Qg + (size_t)jp * 64 * QKV3 + k0, lQ + jp * 4096);
#pragma unroll
        for (int jp = 0; jp < 4; jp++)
            gload16(Kg + (size_t)jp * 64 * QKV3 + k0, lK + jp * 4096);
        __syncthreads();
#pragma unroll
        for (int ks = 0; ks < 2; ks++) {
            bf16x8 af[4], bv[4];
#pragma unroll
            for (int i = 0; i < 4; i++) {
                const int rl = wr * 64 + i * 16 + fr;
                af[i] = *(const bf16x8*)&Qs[rl * 64 + ((((ks << 2) | fq) ^ (rl & 7)) << 3)];
            }
#pragma unroll
            for (int j = 0; j < 4; j++) {
                const int rl = wc * 64 + j * 16 + fr;
                bv[j] = *(const bf16x8*)&Ks[rl * 64 + ((((ks << 2) | fq) ^ (rl & 7)) << 3)];
            }
#pragma unroll
            for (int i = 0; i < 4; i++)
#pragma unroll
                for (int j = 0; j < 4; j++)
                    acc[i][j] = __builtin_amdgcn_mfma_f32_16x16x32_bf16(af[i], bv[j], acc[i][j], 0, 0, 0);
        }
        __syncthreads();
    }
    const float scale = 1.f / 14.f;
    float mx[4][4];
#pragma unroll
    for (int i = 0; i < 4; i++)
#pragma unroll
        for (int r = 0; r < 4; r++) {
            float m0 = -3e30f;
#pragma unroll
            for (int j = 0; j < 4; j++) {
                const int m = wc * 64 + j * 16 + fr;
                float v = (m < Nh) ? acc[i][j][r] * scale : -3e30f;
                acc[i][j][r] = v;
                m0 = fmaxf(m0, v);
            }
            m0 = fmaxf(m0, __shfl_xor(m0, 1));
            m0 = fmaxf(m0, __shfl_xor(m0, 2));
            m0 = fmaxf(m0, __shfl_xor(m0, 4));
            m0 = fmaxf(m0, __shfl_xor(m0, 8));
            mx[i][r] = m0;
        }
    if (fr == 0) {
#pragma unroll
        for (int i = 0; i < 4; i++)
#pragma unroll
            for (int r = 0; r < 4; r++) redM[wr][i * 16 + fq * 4 + r][wc] = mx[i][r];
    }
    __syncthreads();
    float sm[4][4];
#pragma unroll
    for (int i = 0; i < 4; i++)
#pragma unroll
        for (int r = 0; r < 4; r++) {
            const int row = i * 16 + fq * 4 + r;
            const float rm = fmaxf(fmaxf(redM[wr][row][0], redM[wr][row][1]),
                                   fmaxf(redM[wr][row][2], redM[wr][row][3]));
            float s0 = 0.f;
#pragma unroll
            for (int j = 0; j < 4; j++) {
                const float e = expf(acc[i][j][r] - rm);
                acc[i][j][r] = e;
                s0 += e;
            }
            s0 += __shfl_xor(s0, 1);
            s0 += __shfl_xor(s0, 2);
            s0 += __shfl_xor(s0, 4);
            s0 += __shfl_xor(s0, 8);
            sm[i][r] = s0;
        }
    if (fr == 0) {
#pragma unroll
        for (int i = 0; i < 4; i++)
#pragma unroll
            for (int r = 0; r < 4; r++) redS[wr][i * 16 + fq * 4 + r][wc] = sm[i][r];
    }
    __syncthreads();
    bf16* Pb = P + ((size_t)(b * Hh + h) * NP + rt * 128) * NP;
#pragma unroll
    for (int i = 0; i < 4; i++)
#pragma unroll
        for (int r = 0; r < 4; r++) {
            const int row = i * 16 + fq * 4 + r;
            const float s = redS[wr][row][0] + redS[wr][row][1] + redS[wr][row][2] + redS[wr][row][3];
            const float inv = 1.f / s;
#pragma unroll
            for (int j = 0; j < 4; j++)
                Pb[(size_t)(wr * 64 + row) * NP + wc * 64 + j * 16 + fr] = (bf16)(acc[i][j][r] * inv);
        }
}

// ---------------- f32 -> bf16 bulk convert (n multiple of 8)
__global__ __launch_bounds__(256) void cvt_k(const float* __restrict__ in, bf16* __restrict__ out, long n) {
    const long i = ((long)blockIdx.x * 256 + threadIdx.x) * 8;
    if (i >= n) return;
    f32x4 a = *(const f32x4*)(in + i);
    f32x4 b = *(const f32x4*)(in + i + 4);
    bf16x8 r;
#pragma unroll
    for (int j = 0; j < 4; j++) { r[j] = (bf16)a[j]; r[j + 4] = (bf16)b[j]; }
    *(bf16x8*)(out + i) = r;
}

// ---------------- f32 -> bf16 strided per-layer convert (fused QKV weight layout)
__global__ __launch_bounds__(256) void cvt_s_k(const float* __restrict__ in, bf16* __restrict__ out,
                                               long perLayer, long dstStride, long dstOff, long total) {
    const long i = ((long)blockIdx.x * 256 + threadIdx.x) * 8;
    if (i >= total) return;
    const long l = i / perLayer, r = i % perLayer;
    f32x4 a = *(const f32x4*)(in + i);
    f32x4 b = *(const f32x4*)(in + i + 4);
    bf16x8 v;
#pragma unroll
    for (int j = 0; j < 4; j++) { v[j] = (bf16)a[j]; v[j + 4] = (bf16)b[j]; }
    *(bf16x8*)(out + l * dstStride + dstOff + r) = v;
}

// ---------------- concat bq|bk|bv per layer -> f32 [12][27648]
__global__ void qkvbias_k(const float* __restrict__ bq, const float* __restrict__ bk,
                          const float* __restrict__ bv, float* __restrict__ dst) {
    const int idx = blockIdx.x * 256 + threadIdx.x;
    if (idx >= Lh * QKV3) return;
    const int l = idx / QKV3, c = idx % QKV3;
    float v;
    if (c < HD) v = bq[l * HD + c];
    else if (c < 2 * HD) v = bk[l * HD + c - HD];
    else v = bv[l * HD + c - 2 * HD];
    dst[idx] = v;
}

// ---------------- patch gather
__global__ void patch_k(const float* __restrict__ images, bf16* __restrict__ patches) {
    const long idx = (long)blockIdx.x * 256 + threadIdx.x;
    if (idx >= (long)NPAT * Dh) return;
    const int r = (int)(idx / Dh), f = (int)(idx % Dh);
    const int b = r / 196, pi = r % 196, h = pi / 14, w = pi % 14;
    const int px = f / 48, rem = f % 48, py = rem / 3, c = rem % 3;
    patches[idx] = (bf16)images[(((long)(b * 3 + c) * 224) + px * 14 + h) * 224 + py * 14 + w];
}

// ---------------- assemble x = concat(cls, tokens) + pos_emb
__global__ void assemble_k(const float* __restrict__ tokens, const float* __restrict__ cls,
                           float* __restrict__ x, bf16* __restrict__ xbf) {
    const long idx = (long)blockIdx.x * 256 + threadIdx.x;
    if (idx >= (long)BN * Dh) return;
    const int r = (int)(idx / Dh), d = (int)(idx % Dh);
    const int b = r / Nh, n = r % Nh;
    const int je = d & ~1;
    const float ang = (float)n / powf(10000.f, (float)je / 768.f);
    const float pe = (d & 1) ? cosf(ang) : sinf(ang);
    const float val = (n == 0) ? (cls[d] + pe)
                               : (tokens[((long)b * 196 + (n - 1)) * Dh + d] + pe);
    x[idx] = val;
    xbf[idx] = (bf16)val;
}

// ---------------- Wm (f32) -> zero-padded bf16 [12][256][2368]
__global__ void wmpad_k(const float* __restrict__ Wm, bf16* __restrict__ WmP) {
    const long idx = (long)blockIdx.x * 256 + threadIdx.x;
    if (idx >= (long)Lh * 256 * FP) return;
    const int l = (int)(idx / (256 * FP));
    const int rem = (int)(idx % (256 * FP));
    const int n = rem / FP, f = rem % FP;
    bf16 v = (bf16)0.f;
    if (n < Nh && f < FHN) v = (bf16)Wm[((long)l * Nh + n) * FHN + f];
    WmP[idx] = v;
}

// ---------------- zero oT K-pad columns
__global__ void otpad_k(bf16* __restrict__ oT, int cb) {
    const int idx = blockIdx.x * 256 + threadIdx.x;
    if (idx >= cb * Dh * 4) return;
    const int b = idx / (Dh * 4), rem = idx % (Dh * 4), e = rem / 4, f = rem % 4;
    oT[((long)b * Dh + e) * FP + FHN + f] = (bf16)0.f;
}

// ---------------- row softmax (fallback path only)
__global__ __launch_bounds__(256) void softmax_k(const float* __restrict__ S, bf16* __restrict__ P) {
    const int tid = threadIdx.x, lane = tid & 63, wv = tid >> 6;
    const long rr = (long)blockIdx.x * 4 + wv;
    const int bh = (int)(rr / Nh), n = (int)(rr % Nh);
    const float* s = S + ((long)bh * Nh + n) * NP;
    bf16* p = P + ((long)bh * NP + n) * NP;
    float v[4]; float mx = -1e30f;
#pragma unroll
    for (int i = 0; i < 4; i++) {
        const int c = lane + i * 64;
        const float t = (c < Nh) ? s[c] * (1.f / 14.f) : -1e30f;
        v[i] = t; mx = fmaxf(mx, t);
    }
    for (int o = 32; o; o >>= 1) mx = fmaxf(mx, __shfl_xor(mx, o));
    float sum = 0.f;
#pragma unroll
    for (int i = 0; i < 4; i++) {
        const int c = lane + i * 64;
        v[i] = (c < Nh) ? expf(v[i] - mx) : 0.f;
        sum += v[i];
    }
    for (int o = 32; o; o >>= 1) sum += __shfl_xor(sum, o);
    const float inv = 1.f / sum;
#pragma unroll
    for (int i = 0; i < 4; i++) p[lane + i * 64] = (bf16)(v[i] * inv);
}

// ---------------- fused residual-add + bias + LayerNorm; in2 = NPART partials
template<int BIAS_ROW, int NPART>
__global__ __launch_bounds__(256) void add_ln_k(
    const float* __restrict__ in1, const float* __restrict__ in2, long pstride,
    const float* __restrict__ bias, const float* __restrict__ gamma, const float* __restrict__ beta,
    float* __restrict__ outF, bf16* __restrict__ outBF,
    float* __restrict__ dst0, float* __restrict__ dst1)
{
    const int r = blockIdx.x;
    const int b = r / Nh, n = r % Nh;
    const long base = (long)r * Dh;
    const int tid = threadIdx.x;
    const float rowb = BIAS_ROW ? bias[n] : 0.f;
    float v[3]; float s = 0.f, s2 = 0.f;
#pragma unroll
    for (int i = 0; i < 3; i++) {
        const int d = tid + 256 * i;
        float t = in1[base + d] + (BIAS_ROW ? rowb : bias[d]);
#pragma unroll
        for (int pp = 0; pp < NPART; pp++) t += in2[pp * pstride + base + d];
        v[i] = t; s += t; s2 += t * t;
    }
    for (int o = 32; o; o >>= 1) { s += __shfl_xor(s, o); s2 += __shfl_xor(s2, o); }
    __shared__ float red[8];
    const int lane = tid & 63, wv = tid >> 6;
    if (lane == 0) { red[wv] = s; red[4 + wv] = s2; }
    __syncthreads();
    s  = red[0] + red[1] + red[2] + red[3];
    s2 = red[4] + red[5] + red[6] + red[7];
    const float mu = s * (1.f / 768.f);
    const float var = s2 * (1.f / 768.f) - mu * mu;
    const float rs = rsqrtf(var + 1e-5f);
    const long ob = ((long)b * 196 + (n - 1)) * Dh;
#pragma unroll
    for (int i = 0; i < 3; i++) {
        const int d = tid + 256 * i;
        const float y = (v[i] - mu) * rs * gamma[d] + beta[d];
        outF[base + d] = y;
        outBF[base + d] = (bf16)y;
        if (n > 0) {
            if (dst0) dst0[ob + d] = y;
            if (dst1) dst1[ob + d] = y;
        }
    }
}

static inline size_t al256(size_t x) { return (x + 255) & ~(size_t)255; }

// ============================================================
extern "C" void kernel_launch(void* const* d_in, const int* in_sizes, int n_in,
                              void* d_out, int out_size, void* d_ws, size_t ws_size,
                              hipStream_t stream) {
    (void)in_sizes; (void)n_in; (void)out_size;
    const float* images = (const float*)d_in[0];
    const float* cls    = (const float*)d_in[1];
    const float* Wp     = (const float*)d_in[2];
    const float* bp     = (const float*)d_in[3];
    const float* Wq     = (const float*)d_in[4];
    const float* bq     = (const float*)d_in[5];
    const float* Wk     = (const float*)d_in[6];
    const float* bk     = (const float*)d_in[7];
    const float* Wv     = (const float*)d_in[8];
    const float* bv     = (const float*)d_in[9];
    const float* Wm     = (const float*)d_in[10];
    const float* bm     = (const float*)d_in[11];
    const float* g1     = (const float*)d_in[12];
    const float* be1    = (const float*)d_in[13];
    const float* W1     = (const float*)d_in[14];
    const float* b1     = (const float*)d_in[15];
    const float* W2     = (const float*)d_in[16];
    const float* b2     = (const float*)d_in[17];
    const float* g2     = (const float*)d_in[18];
    const float* be2    = (const float*)d_in[19];
    float* out = (float*)d_out;

    // ---- persistent sizes ----
    const size_t xB    = al256(3152ull * 768 * 4);
    const size_t xbfB  = al256(3328ull * 768 * 2);
    const size_t x1B   = al256(3152ull * 768 * 4);
    const size_t x1bfB = al256(3200ull * 768 * 2);
    const size_t msaB  = al256(4ull * PART * 4);
    const size_t mlp2B = al256(4ull * PART * 4);
    const size_t wmpB  = al256(12ull * 256 * FP * 2);
    const size_t biasB = al256((size_t)Lh * QKV3 * 4);
    const size_t persistB = xB + xbfB + x1B + x1bfB + msaB + mlp2B + wmpB + biasB;
    const size_t hdnB  = al256(3200ull * 3072 * 2);
    const size_t preB  = al256(3200ull * 768 * 2) + al256(3136ull * 768 * 4);
    const size_t wqkvB = al256((size_t)Lh * HD * Dh * 2);
    const size_t w12B  = al256((size_t)Lh * Mh * Dh * 2);
    const size_t wpB   = al256(768ull * 768 * 2);
    const size_t weightsB = 3 * wqkvB + 2 * w12B + wpB;

    // ---- fused (QKV big-GEMM) chunk sizes ----
    const size_t qkvbB = al256(3328ull * QKV3 * 2);
    const size_t vtBf  = al256((size_t)Bh * Hh * Dh * NP * 2);
    const size_t pBf   = al256((size_t)Bh * Hh * NP * NP * 2);
    const size_t otBf  = al256((size_t)Bh * Dh * FP * 2);
    size_t chunkF = qkvbB + vtBf + pBf + otBf;
    if (chunkF < hdnB) chunkF = hdnB;
    if (chunkF < preB) chunkF = preB;
    const size_t margin = (size_t)(8u << 20);
    const bool fused = (chunkF + persistB + weightsB + margin <= ws_size);

    // ---- fallback chunk picking ----
    auto chunk_bytes = [&](int cb, size_t& qbB_o, size_t& vtB_o, size_t& sB_o) -> size_t {
        const size_t qbRows = (size_t)((cb * 197 + 127) / 128 + 1) * 128;
        size_t qbB = al256(qbRows * HD * 2);
        size_t vtB = al256((size_t)cb * Hh * Dh * NP * 2);
        size_t sB  = al256((size_t)cb * Hh * Nh * NP * 4);
        size_t c = 2 * qbB + vtB + sB;
        if (c < hdnB) c = hdnB;
        if (c < preB) c = preB;
        qbB_o = qbB; vtB_o = vtB; sB_o = sB;
        return c;
    };
    int CB = 16; bool useCvt = true;
    size_t qbB, vtB, sB, chunkB;
    if (fused) {
        chunkB = chunkF; qbB = vtB = sB = 0;
    } else {
        for (;;) {
            chunkB = chunk_bytes(CB, qbB, vtB, sB);
            if (chunkB + persistB + weightsB + margin <= ws_size) break;
            if (CB == 1) { useCvt = false; break; }
            CB >>= 1;
        }
        if (!useCvt) {
            CB = 16;
            for (;;) {
                chunkB = chunk_bytes(CB, qbB, vtB, sB);
                if (chunkB + persistB + margin <= ws_size || CB == 1) break;
                CB >>= 1;
            }
        }
    }

    // ---- pointers ----
    char* wsb = (char*)d_ws;
    bf16*  qkvb = (bf16*)wsb;
    bf16*  vT2  = (bf16*)(wsb + qkvbB);
    bf16*  P2   = (bf16*)(wsb + qkvbB + vtBf);
    bf16*  oT2  = (bf16*)(wsb + qkvbB + vtBf + pBf);
    bf16*  qb  = (bf16*)wsb;
    bf16*  kb  = (bf16*)(wsb + qbB);
    bf16*  vTf = (bf16*)(wsb + 2 * qbB);
    float* S   = (float*)(wsb + 2 * qbB + vtB);
    bf16*  vT  = fused ? vT2 : vTf;
    bf16*  oT  = fused ? oT2 : qb;
    bf16*  P   = fused ? P2  : kb;
    bf16*  hdn = (bf16*)wsb;
    bf16*  patches = (bf16*)wsb;
    float* tokens  = (float*)(wsb + al256(3200ull * 768 * 2));
    char* p = wsb + chunkB;
    float* x    = (float*)p; p += xB;
    bf16*  xbf  = (bf16*) p; p += xbfB;
    float* x1   = (float*)p; p += x1B;
    bf16*  x1bf = (bf16*) p; p += x1bfB;
    float* msaP = (float*)p; p += msaB;
    float* mlp2P= (float*)p; p += mlp2B;
    bf16*  WmP  = (bf16*) p; p += wmpB;
    float* qkvbias = (float*)p; p += biasB;
    bf16 *WqkvB = nullptr, *W1B = nullptr, *W2B = nullptr, *WpB = nullptr;
    const bool cvt = fused || useCvt;
    if (cvt) {
        WqkvB = (bf16*)p; p += 3 * wqkvB;
        W1B  = (bf16*)p; p += w12B;
        W2B  = (bf16*)p; p += w12B;
        WpB  = (bf16*)p; p += wpB;
    }

    // ---- weight conversion ----
    if (cvt) {
        const long nqkv = (long)Lh * HD * Dh;
        const long n12  = (long)Lh * Mh * Dh;
        const int gq = (int)((nqkv / 8 + 255) / 256);
        const int g12 = (int)((n12 / 8 + 255) / 256);
        cvt_s_k<<<gq, 256, 0, stream>>>(Wq, WqkvB, (long)HD * Dh, LS3, 0, nqkv);
        cvt_s_k<<<gq, 256, 0, stream>>>(Wk, WqkvB, (long)HD * Dh, LS3, (long)HD * Dh, nqkv);
        cvt_s_k<<<gq, 256, 0, stream>>>(Wv, WqkvB, (long)HD * Dh, LS3, 2L * HD * Dh, nqkv);
        cvt_k<<<g12, 256, 0, stream>>>(W1, W1B, n12);
        cvt_k<<<g12, 256, 0, stream>>>(W2, W2B, n12);
        cvt_k<<<(768 * 768 / 8 + 255) / 256, 256, 0, stream>>>(Wp, WpB, 768 * 768);
        qkvbias_k<<<(Lh * QKV3 + 255) / 256, 256, 0, stream>>>(bq, bk, bv, qkvbias);
    }

    // ---- prep ----
    patch_k<<<9408, 256, 0, stream>>>(images, patches);
    if (cvt)
        gemm_bt<0, 0, 0, 1, 0, 0><<<dim3(25 * 6), 256, 0, stream>>>(
            patches, 0, 0, 768, WpB, 0, 0, 768, tokens, 0, 0, 768, bp, 0, NPAT, 768, 768, 6, 0);
    else
        gemm_bt<0, 1, 0, 1, 0, 0><<<dim3(25 * 6), 256, 0, stream>>>(
            patches, 0, 0, 768, Wp, 0, 0, 768, tokens, 0, 0, 768, bp, 0, NPAT, 768, 768, 6, 0);
    assemble_k<<<9456, 256, 0, stream>>>(tokens, cls, x, xbf);
    wmpad_k<<<28416, 256, 0, stream>>>(Wm, WmP);
    if (fused) otpad_k<<<16 * 12, 256, 0, stream>>>(oT2, 16);

    const int NCH = 16 / CB;
    const int tilesQ = (CB * 197 + 127) / 128;

    for (int l = 0; l < 12; l++) {
        const float* Wq_l = Wq + (size_t)l * HD * Dh;
        const float* Wk_l = Wk + (size_t)l * HD * Dh;
        const float* Wv_l = Wv + (size_t)l * HD * Dh;
        const bf16* Wqkv_l = cvt ? WqkvB + (size_t)l * LS3 : nullptr;
        const bf16* WqB_l = Wqkv_l;
        const bf16* WkB_l = cvt ? Wqkv_l + (size_t)HD * Dh : nullptr;
        const bf16* WvB_l = cvt ? Wqkv_l + 2 * (size_t)HD * Dh : nullptr;
        const float* bq_l = bq + (size_t)l * HD;
        const float* bk_l = bk + (size_t)l * HD;
        const float* bv_l = bv + (size_t)l * HD;
        const bf16*  WmP_l = WmP + (size_t)l * 256 * FP;
        const float* bm_l = bm + (size_t)l * Nh;
        const float* g1_l = g1 + (size_t)l * Dh;  const float* be1_l = be1 + (size_t)l * Dh;
        const float* W1_l = W1 + (size_t)l * Mh * Dh; const float* b1_l = b1 + (size_t)l * Mh;
        const float* W2_l = W2 + (size_t)l * Dh * Mh; const float* b2_l = b2 + (size_t)l * Dh;
        const bf16* W1B_l = cvt ? W1B + (size_t)l * Mh * Dh : nullptr;
        const bf16* W2B_l = cvt ? W2B + (size_t)l * Mh * Dh : nullptr;
        const float* g2_l = g2 + (size_t)l * Dh;  const float* be2_l = be2 + (size_t)l * Dh;

        if (fused) {
            // fused Q|K|V in ONE 128x128/BK64 dispatch: C[3152][27648]
            gemm_bt<0, 0, 1, 1, 0, 0><<<dim3(25 * 216), 256, 0, stream>>>(
                xbf, 0, 0, 768, Wqkv_l, 0, 0, 768, qkvb, 0, 0, QKV3,
                qkvbias + (size_t)l * QKV3, 0, BN, QKV3, 768, 216, 0);
            // merged scores+softmax (rt<2) and V-transpose (rt>=2)
            qksoftv_k<<<dim3(26, Hh, Bh), 512, 0, stream>>>(qkvb, P, vT);
            gemm_bt<0, 0, 1, 0, 0, 0><<<dim3(12, 12, 16), 256, 0, stream>>>(
                vT, (long)Dh * NP, (long)Hh * Dh * NP, NP,
                P, (long)NP * NP, (long)Hh * NP * NP, NP,
                oT, (long)Nh, (long)Dh * FP, FP,
                nullptr, 0, Dh, Nh, NP, 2, 0);
            // msa split-K 4 x (640,640,640,448) -> partials msaP[y]
            gemm_bt<0, 0, 0, 0, 0, 0><<<dim3(12, 4, 16), 256, 0, stream>>>(
                WmP_l, 0, 0, FP,
                oT, 0, (long)Dh * FP, FP,
                msaP, PART, (long)Nh * Dh, Dh,
                nullptr, 0, Nh, Dh, FP, 6, 640);
        } else {
            for (int c = 0; c < NCH; c++) {
                const size_t r0 = (size_t)c * CB * Nh;
                if (useCvt) {
                    gemm_bt<0, 0, 1, 1, 0, 0><<<dim3(tilesQ * 72), 256, 0, stream>>>(
                        xbf + r0 * Dh, 0, 0, 768, WqB_l, 0, 0, 768, qb, 0, 0, HD, bq_l, 0, CB * Nh, HD, 768, 72, 0);
                    gemm_bt<0, 0, 1, 1, 0, 0><<<dim3(tilesQ * 72), 256, 0, stream>>>(
                        xbf + r0 * Dh, 0, 0, 768, WkB_l, 0, 0, 768, kb, 0, 0, HD, bk_l, 0, CB * Nh, HD, 768, 72, 0);
                    gemm_bt<0, 0, 1, 2, 0, 1><<<dim3(12, 12, CB), 256, 0, stream>>>(
                        WvB_l, (long)Dh * Dh, 0, 768,
                        xbf + r0 * Dh, 0, (long)Nh * Dh, 768,
                        vT, (long)Dh * NP, (long)Hh * Dh * NP, NP,
                        bv_l, Dh, 768, Nh, 768, 2, 0);
                } else {
                    gemm_bt<0, 1, 1, 1, 0, 0><<<dim3(tilesQ * 72), 256, 0, stream>>>(
                        xbf + r0 * Dh, 0, 0, 768, Wq_l, 0, 0, 768, qb, 0, 0, HD, bq_l, 0, CB * Nh, HD, 768, 72, 0);
                    gemm_bt<0, 1, 1, 1, 0, 0><<<dim3(tilesQ * 72), 256, 0, stream>>>(
                        xbf + r0 * Dh, 0, 0, 768, Wk_l, 0, 0, 768, kb, 0, 0, HD, bk_l, 0, CB * Nh, HD, 768, 72, 0);
                    gemm_bt<1, 0, 1, 2, 0, 1><<<dim3(12, 12, CB), 256, 0, stream>>>(
                        Wv_l, (long)Dh * Dh, 0, 768,
                        xbf + r0 * Dh, 0, (long)Nh * Dh, 768,
                        vT, (long)Dh * NP, (long)Hh * Dh * NP, NP,
                        bv_l, Dh, 768, Nh, 768, 2, 0);
                }
                gemm_bt<0, 0, 0, 0, 0, 0><<<dim3(4, 12, CB), 256, 0, stream>>>(
                    qb, Dh, (long)Nh * HD, HD,
                    kb, Dh, (long)Nh * HD, HD,
                    S, (long)Nh * NP, (long)Hh * Nh * NP, NP,
                    nullptr, 0, Nh, Nh, 768, 2, 0);
                softmax_k<<<CB * 591, 256, 0, stream>>>(S, P);
                otpad_k<<<CB * 12, 256, 0, stream>>>(oT, CB);
                gemm_bt<0, 0, 1, 0, 0, 0><<<dim3(12, 12, CB), 256, 0, stream>>>(
                    vT, (long)Dh * NP, (long)Hh * Dh * NP, NP,
                    P, (long)NP * NP, (long)Hh * NP * NP, NP,
                    oT, (long)Nh, (long)Dh * FP, FP,
                    nullptr, 0, Dh, Nh, NP, 2, 0);
                gemm_bt<0, 0, 0, 0, 0, 0><<<dim3(12, 4, CB), 256, 0, stream>>>(
                    WmP_l, 0, 0, FP,
                    oT, 0, (long)Dh * FP, FP,
                    msaP + r0 * Dh, PART, (long)Nh * Dh, Dh,
                    nullptr, 0, Nh, Dh, FP, 6, 640);
            }
        }
        // x1 = LN(x0 + Σ msaP + bm[n]) * g1 + be1
        add_ln_k<1, 4><<<BN, 256, 0, stream>>>(x, msaP, PART, bm_l, g1_l, be1_l, x1, x1bf, nullptr, nullptr);
        // MLP
        if (cvt) {
            gemm_bt<0, 0, 1, 1, 1, 0><<<dim3(25 * 24), 256, 0, stream>>>(
                x1bf, 0, 0, 768, W1B_l, 0, 0, 768, hdn, 0, 0, Mh, b1_l, 0, BN, Mh, 768, 24, 0);
            gemm_bt<0, 0, 0, 0, 0, 0><<<dim3(25 * 6, 4, 1), 256, 0, stream>>>(
                hdn, 0, 0, Mh, W2B_l, 0, 0, Mh, mlp2P, PART, 0, Dh, nullptr, 0, BN, Dh, Mh, 6, 768);
        } else {
            gemm_bt<0, 1, 1, 1, 1, 0><<<dim3(25 * 24), 256, 0, stream>>>(
                x1bf, 0, 0, 768, W1_l, 0, 0, 768, hdn, 0, 0, Mh, b1_l, 0, BN, Mh, 768, 24, 0);
            gemm_bt<0, 1, 0, 0, 0, 0><<<dim3(25 * 6, 4, 1), 256, 0, stream>>>(
                hdn, 0, 0, Mh, W2_l, 0, 0, Mh, mlp2P, PART, 0, Dh, nullptr, 0, BN, Dh, Mh, 6, 768);
        }
        // out = LN(x1 + Σ mlp2P + b2[d]) * g2 + be2 ; skip writes
        float* d0 = nullptr; float* d1 = nullptr;
        if (l == 2)  d0 = out + 1 * SEC;
        if (l == 5)  d0 = out + 2 * SEC;
        if (l == 8)  d0 = out + 3 * SEC;
        if (l == 11) { d0 = out; d1 = out + 4 * SEC; }
        add_ln_k<0, 4><<<BN, 256, 0, stream>>>(x1, mlp2P, PART, b2_l, g2_l, be2_l, x, xbf, d0, d1);
    }
}

// Round 17
// 5579.690 us; speedup vs baseline: 1.0105x; 1.0105x over previous
//
#include <hip/hip_runtime.h>
#include <cstdint>
#include <cstddef>

typedef __bf16 bf16;
typedef __bf16 bf16x8 __attribute__((ext_vector_type(8)));
typedef float f32x4 __attribute__((ext_vector_type(4)));

#define DEVINL __device__ __forceinline__

typedef const __attribute__((address_space(1))) void* as1cv;
typedef __attribute__((address_space(3))) void* as3v;

DEVINL void gload16(const bf16* g, bf16* l) {
    __builtin_amdgcn_global_load_lds((as1cv)g, (as3v)l, 16, 0, 0);
}

// ---------------- dims ----------------
static constexpr int Lh = 12, Hh = 12, Dh = 768, Nh = 197, Mh = 3072, Bh = 16;
static constexpr int BN   = Bh * Nh;     // 3152 token rows
static constexpr int NPAT = Bh * 196;    // 3136 patch rows
static constexpr int HD   = Hh * Dh;     // 9216
static constexpr int QKN  = 2 * HD;      // 18432 (fallback fused Q|K layout)
static constexpr int QKV3 = 3 * HD;      // 27648 fused Q|K|V cols
static constexpr int NP   = 256;         // padded token dim (attention)
static constexpr int FHN  = Hh * Nh;     // 2364
static constexpr int FP   = 2368;        // padded H*N (mult of 64)
static constexpr size_t SEC = (size_t)Bh * 196 * Dh;  // one output section (f32)
static constexpr long LS3 = (long)QKV3 * Dh;          // fused weight layer stride
static constexpr long PART = (long)BN * Dh;           // split-K partial stride (f32 elems)

// ============================================================
// 128x128-tile GEMM, BK=64, XOR-swizzled LDS (T2, rule #21 both-sides):
// bf16 staging keeps global_load_lds dest LINEAR and pre-swizzles the global
// source chunk (lane&7)^(lane>>3); f32 staging swizzles its ds_write dest;
// fragment reads XOR the 8-elem chunk index with row&7 -> 2-way max (free).
// ============================================================
template<int AF32, int BF32, int OUTBF, int BIAS, int ACT, int ZFILL>
__global__ __launch_bounds__(256, 4) void gemm_bt(
    const void* __restrict__ Av, long sAy, long sAz, int lda,
    const void* __restrict__ Bv, long sBy, long sBz, int ldb,
    void* __restrict__ Cv, long sCy, long sCz, int ldc,
    const float* __restrict__ bias, long sBiasY,
    int Mv, int Nv, int K, int tilesN, int kChunk)
{
    __shared__ __align__(16) bf16 Asm[128 * 64];
    __shared__ __align__(16) bf16 Bsm[128 * 64];
    const int tm = blockIdx.x / tilesN, tn = blockIdx.x % tilesN;
    const long aoff = (long)blockIdx.y * sAy + (long)blockIdx.z * sAz + (long)tm * 128 * lda;
    const long boff = (long)blockIdx.y * sBy + (long)blockIdx.z * sBz + (long)tn * 128 * ldb;
    const int tid = threadIdx.x;
    const int lane = tid & 63, wid = tid >> 6;
    const int ar = tid >> 3;                         // 32 rows per staging pass
    const int ac = (tid & 7) << 3;                   // linear chunk (f32 path src)
    const int acs = (((tid & 7) ^ ((tid >> 3) & 7)) << 3); // swizzled src chunk (bf16 path)
    const bf16* Ag = (const bf16*)Av + aoff + (long)ar * lda + acs;
    const bf16* Bg = (const bf16*)Bv + boff + (long)ar * ldb + acs;
    const float* Af = (const float*)Av + aoff + (long)ar * lda + ac;
    const float* Bf = (const float*)Bv + boff + (long)ar * ldb + ac;
    bf16* lA = Asm + wid * 512;   // wave-uniform base (+lane*16B by HW); pass adds 2048
    bf16* lB = Bsm + wid * 512;
    const int mw = (wid >> 1) * 64, nw = (wid & 1) * 64;
    const int fr = lane & 15, fq = lane >> 4;
    const int kBeg = kChunk ? blockIdx.y * kChunk : 0;
    const int kEnd = kChunk ? min(K, kBeg + kChunk) : K;
    f32x4 acc[4][4] = {};
    for (int k0 = kBeg; k0 < kEnd; k0 += 64) {
        if (AF32) {
#pragma unroll
            for (int jp = 0; jp < 4; jp++) {
                const float* p0 = Af + (long)jp * 32 * lda + k0;
                f32x4 a0 = *(const f32x4*)p0, a1 = *(const f32x4*)(p0 + 4);
                bf16x8 r0;
#pragma unroll
                for (int i = 0; i < 4; i++) { r0[i] = (bf16)a0[i]; r0[i + 4] = (bf16)a1[i]; }
                *(bf16x8*)&Asm[(jp * 32 + ar) * 64 + (ac ^ ((ar & 7) << 3))] = r0;
            }
        } else {
#pragma unroll
            for (int jp = 0; jp < 4; jp++)
                gload16(Ag + (long)jp * 32 * lda + k0, lA + jp * 2048);
        }
        if (BF32) {
#pragma unroll
            for (int jp = 0; jp < 4; jp++) {
                const float* p0 = Bf + (long)jp * 32 * ldb + k0;
                f32x4 a0 = *(const f32x4*)p0, a1 = *(const f32x4*)(p0 + 4);
                bf16x8 r0;
#pragma unroll
                for (int i = 0; i < 4; i++) { r0[i] = (bf16)a0[i]; r0[i + 4] = (bf16)a1[i]; }
                *(bf16x8*)&Bsm[(jp * 32 + ar) * 64 + (ac ^ ((ar & 7) << 3))] = r0;
            }
        } else {
#pragma unroll
            for (int jp = 0; jp < 4; jp++)
                gload16(Bg + (long)jp * 32 * ldb + k0, lB + jp * 2048);
        }
        __syncthreads();
#pragma unroll
        for (int ks = 0; ks < 2; ks++) {
            bf16x8 af[4], bv[4];
#pragma unroll
            for (int i = 0; i < 4; i++) {
                const int rl = mw + i * 16 + fr;
                af[i] = *(const bf16x8*)&Asm[rl * 64 + ((((ks << 2) | fq) ^ (rl & 7)) << 3)];
            }
#pragma unroll
            for (int j = 0; j < 4; j++) {
                const int rl = nw + j * 16 + fr;
                bv[j] = *(const bf16x8*)&Bsm[rl * 64 + ((((ks << 2) | fq) ^ (rl & 7)) << 3)];
            }
#pragma unroll
            for (int i = 0; i < 4; i++)
#pragma unroll
                for (int j = 0; j < 4; j++)
                    acc[i][j] = __builtin_amdgcn_mfma_f32_16x16x32_bf16(af[i], bv[j], acc[i][j], 0, 0, 0);
        }
        __syncthreads();
    }
    const long cb = (long)blockIdx.y * sCy + (long)blockIdx.z * sCz;
    const float* biasp = bias ? bias + (long)blockIdx.y * sBiasY : nullptr;
#pragma unroll
    for (int i = 0; i < 4; i++) {
        const int row0 = tm * 128 + mw + i * 16 + fq * 4;
#pragma unroll
        for (int j = 0; j < 4; j++) {
            const int col = tn * 128 + nw + j * 16 + fr;
            const bool cok = (col < Nv);
            if (!cok && !ZFILL) continue;
            float bc = (BIAS == 1 && cok) ? biasp[col] : 0.f;
#pragma unroll
            for (int r = 0; r < 4; r++) {
                const int rr = row0 + r;
                if (rr >= Mv) continue;
                float v;
                if (cok) {
                    v = acc[i][j][r];
                    if (BIAS == 1) v += bc;
                    if (BIAS == 2) v += biasp[rr];
                    if (ACT) v = 0.5f * v * (1.f + erff(v * 0.70710678118654752f));
                } else v = 0.f;
                const long ci = cb + (long)rr * ldc + col;
                if (OUTBF) ((bf16*)Cv)[ci] = (bf16)v;
                else       ((float*)Cv)[ci] = v;
            }
        }
    }
}

// ============================================================
// Fused scores + row-softmax from qkvb[.][27648], BK=64 + swizzled LDS:
// P[bh][n][m] = softmax_m(Q_bh[n]·K_bh[m] / 14)
// ============================================================
__global__ __launch_bounds__(512, 2) void qksoft_k(
    const bf16* __restrict__ qkb, bf16* __restrict__ P)
{
    __shared__ __align__(16) bf16 Qs[128 * 64];
    __shared__ __align__(16) bf16 Ks[256 * 64];
    __shared__ float redM[2][64][4];
    __shared__ float redS[2][64][4];
    const int rt = blockIdx.x, h = blockIdx.y, b = blockIdx.z;
    const int tid = threadIdx.x;
    const int lane = tid & 63, wid = tid >> 6;
    const int wr = wid >> 2, wc = wid & 3;
    const int fr = lane & 15, fq = lane >> 4;
    const int ar = tid >> 3;                          // 64 rows per staging pass
    const int acs = (((tid & 7) ^ ((tid >> 3) & 7)) << 3);
    const bf16* Qg = qkb + ((size_t)b * Nh + rt * 128 + ar) * QKV3 + h * Dh + acs;
    const bf16* Kg = qkb + ((size_t)b * Nh + ar) * QKV3 + HD + h * Dh + acs;
    bf16* lQ = Qs + wid * 512;
    bf16* lK = Ks + wid * 512;
    f32x4 acc[4][4] = {};
    for (int k0 = 0; k0 < 768; k0 += 64) {
#pragma unroll
        for (int jp = 0; jp < 2; jp++)
            gload16(Qg + (size_t)jp * 64 * QKV3 + k0, lQ + jp * 4096);
#pragma unroll
        for (int jp = 0; jp < 4; jp++)
            gload16(Kg + (size_t)jp * 64 * QKV3 + k0, lK + jp * 4096);
        __syncthreads();
#pragma unroll
        for (int ks = 0; ks < 2; ks++) {
            bf16x8 af[4], bv[4];
#pragma unroll
            for (int i = 0; i < 4; i++) {
                const int rl = wr * 64 + i * 16 + fr;
                af[i] = *(const bf16x8*)&Qs[rl * 64 + ((((ks << 2) | fq) ^ (rl & 7)) << 3)];
            }
#pragma unroll
            for (int j = 0; j < 4; j++) {
                const int rl = wc * 64 + j * 16 + fr;
                bv[j] = *(const bf16x8*)&Ks[rl * 64 + ((((ks << 2) | fq) ^ (rl & 7)) << 3)];
            }
#pragma unroll
            for (int i = 0; i < 4; i++)
#pragma unroll
                for (int j = 0; j < 4; j++)
                    acc[i][j] = __builtin_amdgcn_mfma_f32_16x16x32_bf16(af[i], bv[j], acc[i][j], 0, 0, 0);
        }
        __syncthreads();
    }
    const float scale = 1.f / 14.f;
    float mx[4][4];
#pragma unroll
    for (int i = 0; i < 4; i++)
#pragma unroll
        for (int r = 0; r < 4; r++) {
            float m0 = -3e30f;
#pragma unroll
            for (int j = 0; j < 4; j++) {
                const int m = wc * 64 + j * 16 + fr;
                float v = (m < Nh) ? acc[i][j][r] * scale : -3e30f;
                acc[i][j][r] = v;
                m0 = fmaxf(m0, v);
            }
            m0 = fmaxf(m0, __shfl_xor(m0, 1));
            m0 = fmaxf(m0, __shfl_xor(m0, 2));
            m0 = fmaxf(m0, __shfl_xor(m0, 4));
            m0 = fmaxf(m0, __shfl_xor(m0, 8));
            mx[i][r] = m0;
        }
    if (fr == 0) {
#pragma unroll
        for (int i = 0; i < 4; i++)
#pragma unroll
            for (int r = 0; r < 4; r++) redM[wr][i * 16 + fq * 4 + r][wc] = mx[i][r];
    }
    __syncthreads();
    float sm[4][4];
#pragma unroll
    for (int i = 0; i < 4; i++)
#pragma unroll
        for (int r = 0; r < 4; r++) {
            const int row = i * 16 + fq * 4 + r;
            const float rm = fmaxf(fmaxf(redM[wr][row][0], redM[wr][row][1]),
                                   fmaxf(redM[wr][row][2], redM[wr][row][3]));
            float s0 = 0.f;
#pragma unroll
            for (int j = 0; j < 4; j++) {
                const float e = expf(acc[i][j][r] - rm);
                acc[i][j][r] = e;
                s0 += e;
            }
            s0 += __shfl_xor(s0, 1);
            s0 += __shfl_xor(s0, 2);
            s0 += __shfl_xor(s0, 4);
            s0 += __shfl_xor(s0, 8);
            sm[i][r] = s0;
        }
    if (fr == 0) {
#pragma unroll
        for (int i = 0; i < 4; i++)
#pragma unroll
            for (int r = 0; r < 4; r++) redS[wr][i * 16 + fq * 4 + r][wc] = sm[i][r];
    }
    __syncthreads();
    bf16* Pb = P + ((size_t)(b * Hh + h) * NP + rt * 128) * NP;
#pragma unroll
    for (int i = 0; i < 4; i++)
#pragma unroll
        for (int r = 0; r < 4; r++) {
            const int row = i * 16 + fq * 4 + r;
            const float s = redS[wr][row][0] + redS[wr][row][1] + redS[wr][row][2] + redS[wr][row][3];
            const float inv = 1.f / s;
#pragma unroll
            for (int j = 0; j < 4; j++)
                Pb[(size_t)(wr * 64 + row) * NP + wc * 64 + j * 16 + fr] = (bf16)(acc[i][j][r] * inv);
        }
}

// ---------------- V-transpose: vT[b,h,e,n] = qkvb[b*197+n][2HD+h*768+e]; n>=197 -> 0
__global__ __launch_bounds__(256) void vtrans_k(const bf16* __restrict__ qkv, bf16* __restrict__ vT) {
    __shared__ bf16 t[64][72];
    const int eb = (blockIdx.x >> 2) << 6;
    const int nb = (blockIdx.x & 3) << 6;
    const int h = blockIdx.y, b = blockIdx.z;
    const int tid = threadIdx.x;
    const int lr = tid >> 2;
    const int lc = (tid & 3) << 4;
    const int n = nb + lr;
    if (n < Nh) {
        const bf16* src = qkv + (size_t)(b * Nh + n) * QKV3 + 2 * HD + h * Dh + eb + lc;
        *(bf16x8*)&t[lr][lc] = *(const bf16x8*)src;
        *(bf16x8*)&t[lr][lc + 8] = *(const bf16x8*)(src + 8);
    } else {
        bf16x8 z = {};
        *(bf16x8*)&t[lr][lc] = z; *(bf16x8*)&t[lr][lc + 8] = z;
    }
    __syncthreads();
    bf16* dst = vT + ((size_t)(b * Hh + h) * Dh + eb + lr) * NP + nb + lc;
    bf16x8 o0, o1;
#pragma unroll
    for (int j = 0; j < 8; j++) { o0[j] = t[lc + j][lr]; o1[j] = t[lc + 8 + j][lr]; }
    *(bf16x8*)dst = o0; *(bf16x8*)(dst + 8) = o1;
}

// ---------------- f32 -> bf16 bulk convert (n multiple of 8)
__global__ __launch_bounds__(256) void cvt_k(const float* __restrict__ in, bf16* __restrict__ out, long n) {
    const long i = ((long)blockIdx.x * 256 + threadIdx.x) * 8;
    if (i >= n) return;
    f32x4 a = *(const f32x4*)(in + i);
    f32x4 b = *(const f32x4*)(in + i + 4);
    bf16x8 r;
#pragma unroll
    for (int j = 0; j < 4; j++) { r[j] = (bf16)a[j]; r[j + 4] = (bf16)b[j]; }
    *(bf16x8*)(out + i) = r;
}

// ---------------- f32 -> bf16 strided per-layer convert (fused QKV weight layout)
__global__ __launch_bounds__(256) void cvt_s_k(const float* __restrict__ in, bf16* __restrict__ out,
                                               long perLayer, long dstStride, long dstOff, long total) {
    const long i = ((long)blockIdx.x * 256 + threadIdx.x) * 8;
    if (i >= total) return;
    const long l = i / perLayer, r = i % perLayer;
    f32x4 a = *(const f32x4*)(in + i);
    f32x4 b = *(const f32x4*)(in + i + 4);
    bf16x8 v;
#pragma unroll
    for (int j = 0; j < 4; j++) { v[j] = (bf16)a[j]; v[j + 4] = (bf16)b[j]; }
    *(bf16x8*)(out + l * dstStride + dstOff + r) = v;
}

// ---------------- concat bq|bk|bv per layer -> f32 [12][27648]
__global__ void qkvbias_k(const float* __restrict__ bq, const float* __restrict__ bk,
                          const float* __restrict__ bv, float* __restrict__ dst) {
    const int idx = blockIdx.x * 256 + threadIdx.x;
    if (idx >= Lh * QKV3) return;
    const int l = idx / QKV3, c = idx % QKV3;
    float v;
    if (c < HD) v = bq[l * HD + c];
    else if (c < 2 * HD) v = bk[l * HD + c - HD];
    else v = bv[l * HD + c - 2 * HD];
    dst[idx] = v;
}

// ---------------- patch gather
__global__ void patch_k(const float* __restrict__ images, bf16* __restrict__ patches) {
    const long idx = (long)blockIdx.x * 256 + threadIdx.x;
    if (idx >= (long)NPAT * Dh) return;
    const int r = (int)(idx / Dh), f = (int)(idx % Dh);
    const int b = r / 196, pi = r % 196, h = pi / 14, w = pi % 14;
    const int px = f / 48, rem = f % 48, py = rem / 3, c = rem % 3;
    patches[idx] = (bf16)images[(((long)(b * 3 + c) * 224) + px * 14 + h) * 224 + py * 14 + w];
}

// ---------------- assemble x = concat(cls, tokens) + pos_emb
__global__ void assemble_k(const float* __restrict__ tokens, const float* __restrict__ cls,
                           float* __restrict__ x, bf16* __restrict__ xbf) {
    const long idx = (long)blockIdx.x * 256 + threadIdx.x;
    if (idx >= (long)BN * Dh) return;
    const int r = (int)(idx / Dh), d = (int)(idx % Dh);
    const int b = r / Nh, n = r % Nh;
    const int je = d & ~1;
    const float ang = (float)n / powf(10000.f, (float)je / 768.f);
    const float pe = (d & 1) ? cosf(ang) : sinf(ang);
    const float val = (n == 0) ? (cls[d] + pe)
                               : (tokens[((long)b * 196 + (n - 1)) * Dh + d] + pe);
    x[idx] = val;
    xbf[idx] = (bf16)val;
}

// ---------------- Wm (f32) -> zero-padded bf16 [12][256][2368]
__global__ void wmpad_k(const float* __restrict__ Wm, bf16* __restrict__ WmP) {
    const long idx = (long)blockIdx.x * 256 + threadIdx.x;
    if (idx >= (long)Lh * 256 * FP) return;
    const int l = (int)(idx / (256 * FP));
    const int rem = (int)(idx % (256 * FP));
    const int n = rem / FP, f = rem % FP;
    bf16 v = (bf16)0.f;
    if (n < Nh && f < FHN) v = (bf16)Wm[((long)l * Nh + n) * FHN + f];
    WmP[idx] = v;
}

// ---------------- zero oT K-pad columns
__global__ void otpad_k(bf16* __restrict__ oT, int cb) {
    const int idx = blockIdx.x * 256 + threadIdx.x;
    if (idx >= cb * Dh * 4) return;
    const int b = idx / (Dh * 4), rem = idx % (Dh * 4), e = rem / 4, f = rem % 4;
    oT[((long)b * Dh + e) * FP + FHN + f] = (bf16)0.f;
}

// ---------------- row softmax (fallback path only)
__global__ __launch_bounds__(256) void softmax_k(const float* __restrict__ S, bf16* __restrict__ P) {
    const int tid = threadIdx.x, lane = tid & 63, wv = tid >> 6;
    const long rr = (long)blockIdx.x * 4 + wv;
    const int bh = (int)(rr / Nh), n = (int)(rr % Nh);
    const float* s = S + ((long)bh * Nh + n) * NP;
    bf16* p = P + ((long)bh * NP + n) * NP;
    float v[4]; float mx = -1e30f;
#pragma unroll
    for (int i = 0; i < 4; i++) {
        const int c = lane + i * 64;
        const float t = (c < Nh) ? s[c] * (1.f / 14.f) : -1e30f;
        v[i] = t; mx = fmaxf(mx, t);
    }
    for (int o = 32; o; o >>= 1) mx = fmaxf(mx, __shfl_xor(mx, o));
    float sum = 0.f;
#pragma unroll
    for (int i = 0; i < 4; i++) {
        const int c = lane + i * 64;
        v[i] = (c < Nh) ? expf(v[i] - mx) : 0.f;
        sum += v[i];
    }
    for (int o = 32; o; o >>= 1) sum += __shfl_xor(sum, o);
    const float inv = 1.f / sum;
#pragma unroll
    for (int i = 0; i < 4; i++) p[lane + i * 64] = (bf16)(v[i] * inv);
}

// ---------------- fused residual-add + bias + LayerNorm; in2 = NPART partials
template<int BIAS_ROW, int NPART>
__global__ __launch_bounds__(256) void add_ln_k(
    const float* __restrict__ in1, const float* __restrict__ in2, long pstride,
    const float* __restrict__ bias, const float* __restrict__ gamma, const float* __restrict__ beta,
    float* __restrict__ outF, bf16* __restrict__ outBF,
    float* __restrict__ dst0, float* __restrict__ dst1)
{
    const int r = blockIdx.x;
    const int b = r / Nh, n = r % Nh;
    const long base = (long)r * Dh;
    const int tid = threadIdx.x;
    const float rowb = BIAS_ROW ? bias[n] : 0.f;
    float v[3]; float s = 0.f, s2 = 0.f;
#pragma unroll
    for (int i = 0; i < 3; i++) {
        const int d = tid + 256 * i;
        float t = in1[base + d] + (BIAS_ROW ? rowb : bias[d]);
#pragma unroll
        for (int pp = 0; pp < NPART; pp++) t += in2[pp * pstride + base + d];
        v[i] = t; s += t; s2 += t * t;
    }
    for (int o = 32; o; o >>= 1) { s += __shfl_xor(s, o); s2 += __shfl_xor(s2, o); }
    __shared__ float red[8];
    const int lane = tid & 63, wv = tid >> 6;
    if (lane == 0) { red[wv] = s; red[4 + wv] = s2; }
    __syncthreads();
    s  = red[0] + red[1] + red[2] + red[3];
    s2 = red[4] + red[5] + red[6] + red[7];
    const float mu = s * (1.f / 768.f);
    const float var = s2 * (1.f / 768.f) - mu * mu;
    const float rs = rsqrtf(var + 1e-5f);
    const long ob = ((long)b * 196 + (n - 1)) * Dh;
#pragma unroll
    for (int i = 0; i < 3; i++) {
        const int d = tid + 256 * i;
        const float y = (v[i] - mu) * rs * gamma[d] + beta[d];
        outF[base + d] = y;
        outBF[base + d] = (bf16)y;
        if (n > 0) {
            if (dst0) dst0[ob + d] = y;
            if (dst1) dst1[ob + d] = y;
        }
    }
}

static inline size_t al256(size_t x) { return (x + 255) & ~(size_t)255; }

// ============================================================
extern "C" void kernel_launch(void* const* d_in, const int* in_sizes, int n_in,
                              void* d_out, int out_size, void* d_ws, size_t ws_size,
                              hipStream_t stream) {
    (void)in_sizes; (void)n_in; (void)out_size;
    const float* images = (const float*)d_in[0];
    const float* cls    = (const float*)d_in[1];
    const float* Wp     = (const float*)d_in[2];
    const float* bp     = (const float*)d_in[3];
    const float* Wq     = (const float*)d_in[4];
    const float* bq     = (const float*)d_in[5];
    const float* Wk     = (const float*)d_in[6];
    const float* bk     = (const float*)d_in[7];
    const float* Wv     = (const float*)d_in[8];
    const float* bv     = (const float*)d_in[9];
    const float* Wm     = (const float*)d_in[10];
    const float* bm     = (const float*)d_in[11];
    const float* g1     = (const float*)d_in[12];
    const float* be1    = (const float*)d_in[13];
    const float* W1     = (const float*)d_in[14];
    const float* b1     = (const float*)d_in[15];
    const float* W2     = (const float*)d_in[16];
    const float* b2     = (const float*)d_in[17];
    const float* g2     = (const float*)d_in[18];
    const float* be2    = (const float*)d_in[19];
    float* out = (float*)d_out;

    // ---- persistent sizes ----
    const size_t xB    = al256(3152ull * 768 * 4);
    const size_t xbfB  = al256(3328ull * 768 * 2);
    const size_t x1B   = al256(3152ull * 768 * 4);
    const size_t x1bfB = al256(3200ull * 768 * 2);
    const size_t msaB  = al256(4ull * PART * 4);
    const size_t mlp2B = al256(4ull * PART * 4);
    const size_t wmpB  = al256(12ull * 256 * FP * 2);
    const size_t biasB = al256((size_t)Lh * QKV3 * 4);
    const size_t persistB = xB + xbfB + x1B + x1bfB + msaB + mlp2B + wmpB + biasB;
    const size_t hdnB  = al256(3200ull * 3072 * 2);
    const size_t preB  = al256(3200ull * 768 * 2) + al256(3136ull * 768 * 4);
    const size_t wqkvB = al256((size_t)Lh * HD * Dh * 2);
    const size_t w12B  = al256((size_t)Lh * Mh * Dh * 2);
    const size_t wpB   = al256(768ull * 768 * 2);
    const size_t weightsB = 3 * wqkvB + 2 * w12B + wpB;

    // ---- fused (QKV big-GEMM) chunk sizes ----
    const size_t qkvbB = al256(3328ull * QKV3 * 2);
    const size_t vtBf  = al256((size_t)Bh * Hh * Dh * NP * 2);
    const size_t pBf   = al256((size_t)Bh * Hh * NP * NP * 2);
    const size_t otBf  = al256((size_t)Bh * Dh * FP * 2);
    size_t chunkF = qkvbB + vtBf + pBf + otBf;
    if (chunkF < hdnB) chunkF = hdnB;
    if (chunkF < preB) chunkF = preB;
    const size_t margin = (size_t)(8u << 20);
    const bool fused = (chunkF + persistB + weightsB + margin <= ws_size);

    // ---- fallback chunk picking ----
    auto chunk_bytes = [&](int cb, size_t& qbB_o, size_t& vtB_o, size_t& sB_o) -> size_t {
        const size_t qbRows = (size_t)((cb * 197 + 127) / 128 + 1) * 128;
        size_t qbB = al256(qbRows * HD * 2);
        size_t vtB = al256((size_t)cb * Hh * Dh * NP * 2);
        size_t sB  = al256((size_t)cb * Hh * Nh * NP * 4);
        size_t c = 2 * qbB + vtB + sB;
        if (c < hdnB) c = hdnB;
        if (c < preB) c = preB;
        qbB_o = qbB; vtB_o = vtB; sB_o = sB;
        return c;
    };
    int CB = 16; bool useCvt = true;
    size_t qbB, vtB, sB, chunkB;
    if (fused) {
        chunkB = chunkF; qbB = vtB = sB = 0;
    } else {
        for (;;) {
            chunkB = chunk_bytes(CB, qbB, vtB, sB);
            if (chunkB + persistB + weightsB + margin <= ws_size) break;
            if (CB == 1) { useCvt = false; break; }
            CB >>= 1;
        }
        if (!useCvt) {
            CB = 16;
            for (;;) {
                chunkB = chunk_bytes(CB, qbB, vtB, sB);
                if (chunkB + persistB + margin <= ws_size || CB == 1) break;
                CB >>= 1;
            }
        }
    }

    // ---- pointers ----
    char* wsb = (char*)d_ws;
    bf16*  qkvb = (bf16*)wsb;
    bf16*  vT2  = (bf16*)(wsb + qkvbB);
    bf16*  P2   = (bf16*)(wsb + qkvbB + vtBf);
    bf16*  oT2  = (bf16*)(wsb + qkvbB + vtBf + pBf);
    bf16*  qb  = (bf16*)wsb;
    bf16*  kb  = (bf16*)(wsb + qbB);
    bf16*  vTf = (bf16*)(wsb + 2 * qbB);
    float* S   = (float*)(wsb + 2 * qbB + vtB);
    bf16*  vT  = fused ? vT2 : vTf;
    bf16*  oT  = fused ? oT2 : qb;
    bf16*  P   = fused ? P2  : kb;
    bf16*  hdn = (bf16*)wsb;
    bf16*  patches = (bf16*)wsb;
    float* tokens  = (float*)(wsb + al256(3200ull * 768 * 2));
    char* p = wsb + chunkB;
    float* x    = (float*)p; p += xB;
    bf16*  xbf  = (bf16*) p; p += xbfB;
    float* x1   = (float*)p; p += x1B;
    bf16*  x1bf = (bf16*) p; p += x1bfB;
    float* msaP = (float*)p; p += msaB;
    float* mlp2P= (float*)p; p += mlp2B;
    bf16*  WmP  = (bf16*) p; p += wmpB;
    float* qkvbias = (float*)p; p += biasB;
    bf16 *WqkvB = nullptr, *W1B = nullptr, *W2B = nullptr, *WpB = nullptr;
    const bool cvt = fused || useCvt;
    if (cvt) {
        WqkvB = (bf16*)p; p += 3 * wqkvB;
        W1B  = (bf16*)p; p += w12B;
        W2B  = (bf16*)p; p += w12B;
        WpB  = (bf16*)p; p += wpB;
    }

    // ---- weight conversion ----
    if (cvt) {
        const long nqkv = (long)Lh * HD * Dh;
        const long n12  = (long)Lh * Mh * Dh;
        const int gq = (int)((nqkv / 8 + 255) / 256);
        const int g12 = (int)((n12 / 8 + 255) / 256);
        cvt_s_k<<<gq, 256, 0, stream>>>(Wq, WqkvB, (long)HD * Dh, LS3, 0, nqkv);
        cvt_s_k<<<gq, 256, 0, stream>>>(Wk, WqkvB, (long)HD * Dh, LS3, (long)HD * Dh, nqkv);
        cvt_s_k<<<gq, 256, 0, stream>>>(Wv, WqkvB, (long)HD * Dh, LS3, 2L * HD * Dh, nqkv);
        cvt_k<<<g12, 256, 0, stream>>>(W1, W1B, n12);
        cvt_k<<<g12, 256, 0, stream>>>(W2, W2B, n12);
        cvt_k<<<(768 * 768 / 8 + 255) / 256, 256, 0, stream>>>(Wp, WpB, 768 * 768);
        qkvbias_k<<<(Lh * QKV3 + 255) / 256, 256, 0, stream>>>(bq, bk, bv, qkvbias);
    }

    // ---- prep ----
    patch_k<<<9408, 256, 0, stream>>>(images, patches);
    if (cvt)
        gemm_bt<0, 0, 0, 1, 0, 0><<<dim3(25 * 6), 256, 0, stream>>>(
            patches, 0, 0, 768, WpB, 0, 0, 768, tokens, 0, 0, 768, bp, 0, NPAT, 768, 768, 6, 0);
    else
        gemm_bt<0, 1, 0, 1, 0, 0><<<dim3(25 * 6), 256, 0, stream>>>(
            patches, 0, 0, 768, Wp, 0, 0, 768, tokens, 0, 0, 768, bp, 0, NPAT, 768, 768, 6, 0);
    assemble_k<<<9456, 256, 0, stream>>>(tokens, cls, x, xbf);
    wmpad_k<<<28416, 256, 0, stream>>>(Wm, WmP);
    if (fused) otpad_k<<<16 * 12, 256, 0, stream>>>(oT2, 16);

    const int NCH = 16 / CB;
    const int tilesQ = (CB * 197 + 127) / 128;

    for (int l = 0; l < 12; l++) {
        const float* Wq_l = Wq + (size_t)l * HD * Dh;
        const float* Wk_l = Wk + (size_t)l * HD * Dh;
        const float* Wv_l = Wv + (size_t)l * HD * Dh;
        const bf16* Wqkv_l = cvt ? WqkvB + (size_t)l * LS3 : nullptr;
        const bf16* WqB_l = Wqkv_l;
        const bf16* WkB_l = cvt ? Wqkv_l + (size_t)HD * Dh : nullptr;
        const bf16* WvB_l = cvt ? Wqkv_l + 2 * (size_t)HD * Dh : nullptr;
        const float* bq_l = bq + (size_t)l * HD;
        const float* bk_l = bk + (size_t)l * HD;
        const float* bv_l = bv + (size_t)l * HD;
        const bf16*  WmP_l = WmP + (size_t)l * 256 * FP;
        const float* bm_l = bm + (size_t)l * Nh;
        const float* g1_l = g1 + (size_t)l * Dh;  const float* be1_l = be1 + (size_t)l * Dh;
        const float* W1_l = W1 + (size_t)l * Mh * Dh; const float* b1_l = b1 + (size_t)l * Mh;
        const float* W2_l = W2 + (size_t)l * Dh * Mh; const float* b2_l = b2 + (size_t)l * Dh;
        const bf16* W1B_l = cvt ? W1B + (size_t)l * Mh * Dh : nullptr;
        const bf16* W2B_l = cvt ? W2B + (size_t)l * Mh * Dh : nullptr;
        const float* g2_l = g2 + (size_t)l * Dh;  const float* be2_l = be2 + (size_t)l * Dh;

        if (fused) {
            // fused Q|K|V in ONE 128x128/BK64 dispatch: C[3152][27648]
            gemm_bt<0, 0, 1, 1, 0, 0><<<dim3(25 * 216), 256, 0, stream>>>(
                xbf, 0, 0, 768, Wqkv_l, 0, 0, 768, qkvb, 0, 0, QKV3,
                qkvbias + (size_t)l * QKV3, 0, BN, QKV3, 768, 216, 0);
            vtrans_k<<<dim3(48, 12, 16), 256, 0, stream>>>(qkvb, vT);
            qksoft_k<<<dim3(2, Hh, Bh), 512, 0, stream>>>(qkvb, P);
            gemm_bt<0, 0, 1, 0, 0, 0><<<dim3(12, 12, 16), 256, 0, stream>>>(
                vT, (long)Dh * NP, (long)Hh * Dh * NP, NP,
                P, (long)NP * NP, (long)Hh * NP * NP, NP,
                oT, (long)Nh, (long)Dh * FP, FP,
                nullptr, 0, Dh, Nh, NP, 2, 0);
            // msa split-K 4 x (640,640,640,448) -> partials msaP[y]
            gemm_bt<0, 0, 0, 0, 0, 0><<<dim3(12, 4, 16), 256, 0, stream>>>(
                WmP_l, 0, 0, FP,
                oT, 0, (long)Dh * FP, FP,
                msaP, PART, (long)Nh * Dh, Dh,
                nullptr, 0, Nh, Dh, FP, 6, 640);
        } else {
            for (int c = 0; c < NCH; c++) {
                const size_t r0 = (size_t)c * CB * Nh;
                if (useCvt) {
                    gemm_bt<0, 0, 1, 1, 0, 0><<<dim3(tilesQ * 72), 256, 0, stream>>>(
                        xbf + r0 * Dh, 0, 0, 768, WqB_l, 0, 0, 768, qb, 0, 0, HD, bq_l, 0, CB * Nh, HD, 768, 72, 0);
                    gemm_bt<0, 0, 1, 1, 0, 0><<<dim3(tilesQ * 72), 256, 0, stream>>>(
                        xbf + r0 * Dh, 0, 0, 768, WkB_l, 0, 0, 768, kb, 0, 0, HD, bk_l, 0, CB * Nh, HD, 768, 72, 0);
                    gemm_bt<0, 0, 1, 2, 0, 1><<<dim3(12, 12, CB), 256, 0, stream>>>(
                        WvB_l, (long)Dh * Dh, 0, 768,
                        xbf + r0 * Dh, 0, (long)Nh * Dh, 768,
                        vT, (long)Dh * NP, (long)Hh * Dh * NP, NP,
                        bv_l, Dh, 768, Nh, 768, 2, 0);
                } else {
                    gemm_bt<0, 1, 1, 1, 0, 0><<<dim3(tilesQ * 72), 256, 0, stream>>>(
                        xbf + r0 * Dh, 0, 0, 768, Wq_l, 0, 0, 768, qb, 0, 0, HD, bq_l, 0, CB * Nh, HD, 768, 72, 0);
                    gemm_bt<0, 1, 1, 1, 0, 0><<<dim3(tilesQ * 72), 256, 0, stream>>>(
                        xbf + r0 * Dh, 0, 0, 768, Wk_l, 0, 0, 768, kb, 0, 0, HD, bk_l, 0, CB * Nh, HD, 768, 72, 0);
                    gemm_bt<1, 0, 1, 2, 0, 1><<<dim3(12, 12, CB), 256, 0, stream>>>(
                        Wv_l, (long)Dh * Dh, 0, 768,
                        xbf + r0 * Dh, 0, (long)Nh * Dh, 768,
                        vT, (long)Dh * NP, (long)Hh * Dh * NP, NP,
                        bv_l, Dh, 768, Nh, 768, 2, 0);
                }
                gemm_bt<0, 0, 0, 0, 0, 0><<<dim3(4, 12, CB), 256, 0, stream>>>(
                    qb, Dh, (long)Nh * HD, HD,
                    kb, Dh, (long)Nh * HD, HD,
                    S, (long)Nh * NP, (long)Hh * Nh * NP, NP,
                    nullptr, 0, Nh, Nh, 768, 2, 0);
                softmax_k<<<CB * 591, 256, 0, stream>>>(S, P);
                otpad_k<<<CB * 12, 256, 0, stream>>>(oT, CB);
                gemm_bt<0, 0, 1, 0, 0, 0><<<dim3(12, 12, CB), 256, 0, stream>>>(
                    vT, (long)Dh * NP, (long)Hh * Dh * NP, NP,
                    P, (long)NP * NP, (long)Hh * NP * NP, NP,
                    oT, (long)Nh, (long)Dh * FP, FP,
                    nullptr, 0, Dh, Nh, NP, 2, 0);
                gemm_bt<0, 0, 0, 0, 0, 0><<<dim3(12, 4, CB), 256, 0, stream>>>(
                    WmP_l, 0, 0, FP,
                    oT, 0, (long)Dh * FP, FP,
                    msaP + r0 * Dh, PART, (long)Nh * Dh, Dh,
                    nullptr, 0, Nh, Dh, FP, 6, 640);
            }
        }
        // x1 = LN(x0 + Σ msaP + bm[n]) * g1 + be1
        add_ln_k<1, 4><<<BN, 256, 0, stream>>>(x, msaP, PART, bm_l, g1_l, be1_l, x1, x1bf, nullptr, nullptr);
        // MLP
        if (cvt) {
            gemm_bt<0, 0, 1, 1, 1, 0><<<dim3(25 * 24), 256, 0, stream>>>(
                x1bf, 0, 0, 768, W1B_l, 0, 0, 768, hdn, 0, 0, Mh, b1_l, 0, BN, Mh, 768, 24, 0);
            gemm_bt<0, 0, 0, 0, 0, 0><<<dim3(25 * 6, 4, 1), 256, 0, stream>>>(
                hdn, 0, 0, Mh, W2B_l, 0, 0, Mh, mlp2P, PART, 0, Dh, nullptr, 0, BN, Dh, Mh, 6, 768);
        } else {
            gemm_bt<0, 1, 1, 1, 1, 0><<<dim3(25 * 24), 256, 0, stream>>>(
                x1bf, 0, 0, 768, W1_l, 0, 0, 768, hdn, 0, 0, Mh, b1_l, 0, BN, Mh, 768, 24, 0);
            gemm_bt<0, 1, 0, 0, 0, 0><<<dim3(25 * 6, 4, 1), 256, 0, stream>>>(
                hdn, 0, 0, Mh, W2_l, 0, 0, Mh, mlp2P, PART, 0, Dh, nullptr, 0, BN, Dh, Mh, 6, 768);
        }
        // out = LN(x1 + Σ mlp2P + b2[d]) * g2 + be2 ; skip writes
        float* d0 = nullptr; float* d1 = nullptr;
        if (l == 2)  d0 = out + 1 * SEC;
        if (l == 5)  d0 = out + 2 * SEC;
        if (l == 8)  d0 = out + 3 * SEC;
        if (l == 11) { d0 = out; d1 = out + 4 * SEC; }
        add_ln_k<0, 4><<<BN, 256, 0, stream>>>(x1, mlp2P, PART, b2_l, g2_l, be2_l, x, xbf, d0, d1);
    }
}